// Round 1
// baseline (77.422 us; speedup 1.0000x reference)
//
#include <hip/hip_runtime.h>
#include <math.h>

// Problem constants (fixed by setup_inputs)
#define B_     32
#define K_     16
#define T_     30
#define KT_    480      // K*T pred points per batch
#define N_     128
#define NPN_   20       // nodes per polyline
#define NODES_ 2560     // N*NPN per batch
#define CH_    16       // node chunks per batch
#define CSZ_   160      // nodes per chunk = 8 whole polylines (yaw computable locally)

#define PI_F      3.14159265358979323846f
#define TWO_PI_F  6.28318530717958647692f
#define YAW_TH_F  (PI_F / 3.0f)

// Kernel 1: per (batch, node-chunk) partial min over 160 nodes for all 480 pred
// points. 2 pred points per thread to amortize the LDS broadcast read.
__global__ __launch_bounds__(256) void cm_partial(
    const float* __restrict__ preds,   // (B, K, T, 2)
    const float* __restrict__ cn,      // (B, N, n, 2)
    const int*   __restrict__ cmask,   // (B, N, n)
    float*       __restrict__ ws)      // (B, KT, CH) partial mins
{
  const int b   = blockIdx.x / CH_;
  const int c   = blockIdx.x % CH_;
  const int tid = threadIdx.x;

  __shared__ float4 nd[CSZ_];   // x, y, (||n||^2 or +inf if masked), yaw

  // ---- stage node chunk into LDS ----
  if (tid < CSZ_) {
    const int gn = c * CSZ_ + tid;            // node index within batch
    const int j  = gn % NPN_;                 // position within polyline
    const float2* cnb = (const float2*)cn + (size_t)b * NODES_;
    const float2 p = cnb[gn];
    float yaw = 0.0f;
    if (j != 0) {
      const float2 q = cnb[gn - 1];
      yaw = -atan2f(p.x - q.x, p.y - q.y);    // ref: -arctan2(dx, dy)
    }
    const int mv = cmask[(size_t)b * NODES_ + gn];
    const float a2 = (mv == 1) ? INFINITY : fmaf(p.x, p.x, p.y * p.y);
    nd[tid] = make_float4(p.x, p.y, a2, yaw);
  }

  // ---- per-thread pred point setup (2 points: tid and tid+256) ----
  const int kt0 = tid;          // always < 480
  const int kt1 = tid + 256;    // valid iff < 480
  const float2* pb = (const float2*)preds + (size_t)b * KT_;

  float px20, py20, cb0, pyaw0;
  float px21, py21, cb1, pyaw1;
  {
    const float2 pp = pb[kt0];
    pyaw0 = 0.0f;
    if ((kt0 % T_) != 0) {
      const float2 pq = pb[kt0 - 1];
      pyaw0 = -atan2f(pp.x - pq.x, pp.y - pq.y);
    }
    cb0  = fmaf(pp.x, pp.x, pp.y * pp.y);
    px20 = -2.0f * pp.x;
    py20 = -2.0f * pp.y;
  }
  if (kt1 < KT_) {
    const float2 pp = pb[kt1];
    pyaw1 = 0.0f;
    if ((kt1 % T_) != 0) {
      const float2 pq = pb[kt1 - 1];
      pyaw1 = -atan2f(pp.x - pq.x, pp.y - pq.y);
    }
    cb1  = fmaf(pp.x, pp.x, pp.y * pp.y);
    px21 = -2.0f * pp.x;
    py21 = -2.0f * pp.y;
  } else {
    pyaw1 = 0.0f; cb1 = 0.0f; px21 = 0.0f; py21 = 0.0f;  // benign garbage lane
  }

  __syncthreads();

  // ---- min over the chunk's nodes ----
  float m0 = INFINITY, m1 = INFINITY;
  #pragma unroll 4
  for (int i = 0; i < CSZ_; ++i) {
    const float4 nv = nd[i];   // broadcast read, conflict-free
    {
      float d2 = fmaf(nv.y, py20, fmaf(nv.x, px20, nv.z + cb0));
      d2 = fmaxf(d2, 0.0f);                       // matches ref max(d2,0)
      const float dist = __builtin_amdgcn_sqrtf(d2);
      const float yd = fabsf(nv.w - pyaw0);
      const float a  = fminf(yd, TWO_PI_F - yd);  // == |wrap to [-pi,pi)|
      const float cost = fmaxf(dist - 2.0f, 0.0f) + fmaxf(a - YAW_TH_F, 0.0f);
      m0 = fminf(m0, cost);
    }
    {
      float d2 = fmaf(nv.y, py21, fmaf(nv.x, px21, nv.z + cb1));
      d2 = fmaxf(d2, 0.0f);
      const float dist = __builtin_amdgcn_sqrtf(d2);
      const float yd = fabsf(nv.w - pyaw1);
      const float a  = fminf(yd, TWO_PI_F - yd);
      const float cost = fmaxf(dist - 2.0f, 0.0f) + fmaxf(a - YAW_TH_F, 0.0f);
      m1 = fminf(m1, cost);
    }
  }

  ws[((size_t)b * KT_ + kt0) * CH_ + c] = m0;
  if (kt1 < KT_) ws[((size_t)b * KT_ + kt1) * CH_ + c] = m1;
}

// Kernel 2: min over chunks, then sum over T per (b, k).
__global__ __launch_bounds__(512) void cm_reduce(
    const float* __restrict__ ws, float* __restrict__ out)
{
  const int b   = blockIdx.x;
  const int tid = threadIdx.x;
  __shared__ float sc[KT_];

  if (tid < KT_) {
    const float4* w4 = (const float4*)(ws + ((size_t)b * KT_ + tid) * CH_);
    const float4 v0 = w4[0], v1 = w4[1], v2 = w4[2], v3 = w4[3];
    const float m =
      fminf(fminf(fminf(fminf(v0.x, v0.y), fminf(v0.z, v0.w)),
                  fminf(fminf(v1.x, v1.y), fminf(v1.z, v1.w))),
            fminf(fminf(fminf(v2.x, v2.y), fminf(v2.z, v2.w)),
                  fminf(fminf(v3.x, v3.y), fminf(v3.z, v3.w))));
    sc[tid] = m;
  }
  __syncthreads();

  if (tid < K_) {
    float s = 0.0f;
    #pragma unroll
    for (int t = 0; t < T_; ++t) s += sc[tid * T_ + t];
    out[b * K_ + tid] = s;
  }
}

extern "C" void kernel_launch(void* const* d_in, const int* in_sizes, int n_in,
                              void* d_out, int out_size, void* d_ws, size_t ws_size,
                              hipStream_t stream) {
  const float* preds = (const float*)d_in[0];
  const float* cn    = (const float*)d_in[1];
  const int*   cmask = (const int*)d_in[2];
  float* out = (float*)d_out;
  float* ws  = (float*)d_ws;   // needs B*KT*CH*4 = 983,040 bytes

  cm_partial<<<dim3(B_ * CH_), dim3(256), 0, stream>>>(preds, cn, cmask, ws);
  cm_reduce<<<dim3(B_), dim3(512), 0, stream>>>(ws, out);
}

// Round 2
// 75.992 us; speedup vs baseline: 1.0188x; 1.0188x over previous
//
#include <hip/hip_runtime.h>
#include <math.h>

// Problem constants (fixed by setup_inputs)
#define B_     32
#define K_     16
#define T_     30
#define KT_    480      // K*T pred points per batch
#define N_     128
#define NPN_   20       // nodes per polyline
#define NODES_ 2560     // N*NPN per batch
#define CH_    32       // node chunks per batch
#define CSZ_   80       // nodes per chunk = 4 whole polylines

#define PI_F      3.14159265358979323846f
#define TWO_PI_F  6.28318530717958647692f
#define YAW_TH_F  (PI_F / 3.0f)

#define NNODE_TOT (B_ * NODES_)   // 81920
#define NPT_TOT   (B_ * KT_)      // 15360

// ws layout (float4 elements):
//   nodes:  [0, 81920)                    float4(-2x, -2y, a2-or-inf, yaw)
//   points: [81920, 81920+15360)          float4(px, py, b2, pyaw)
//   partial mins (float): after that, [B][CH][KT]
#define WS_PTS_OFF   NNODE_TOT
#define WS_PART_OFF4 (NNODE_TOT + NPT_TOT)   // in float4 units

// ---------------------------------------------------------------------------
// Kernel 0: preprocess nodes and points (all atan2 / masking happens here)
__global__ __launch_bounds__(256) void cm_prep(
    const float* __restrict__ preds,   // (B, K, T, 2)
    const float* __restrict__ cn,      // (B, N, n, 2)
    const int*   __restrict__ cmask,   // (B, N, n)
    float4*      __restrict__ ws)
{
  const int idx = blockIdx.x * 256 + threadIdx.x;   // grid covers 97280 exactly
  if (idx < NNODE_TOT) {
    const int b  = idx / NODES_;
    const int g  = idx - b * NODES_;
    const int j  = g % NPN_;
    const float2* cnb = (const float2*)cn + (size_t)b * NODES_;
    const float2 p = cnb[g];
    float yaw = 0.0f;
    if (j != 0) {
      const float2 q = cnb[g - 1];
      yaw = -atan2f(p.x - q.x, p.y - q.y);          // ref: -arctan2(dx, dy)
    }
    const int mv = cmask[idx];
    const float a2 = (mv == 1) ? INFINITY : fmaf(p.x, p.x, p.y * p.y);
    ws[idx] = make_float4(-2.0f * p.x, -2.0f * p.y, a2, yaw);
  } else {
    const int i2 = idx - NNODE_TOT;                 // < 15360
    const int b  = i2 / KT_;
    const int kt = i2 - b * KT_;
    const float2* pb = (const float2*)preds + (size_t)b * KT_;
    const float2 pp = pb[kt];
    float pyaw = 0.0f;
    if ((kt % T_) != 0) {
      const float2 pq = pb[kt - 1];
      pyaw = -atan2f(pp.x - pq.x, pp.y - pq.y);
    }
    const float b2 = fmaf(pp.x, pp.x, pp.y * pp.y);
    ws[WS_PTS_OFF + i2] = make_float4(pp.x, pp.y, b2, pyaw);
  }
}

// ---------------------------------------------------------------------------
// Kernel 1: per (batch, chunk) partial min over 80 nodes for all 480 points.
// Per pair (12 VALU ops, -2 hoisted out of the min):
//   s = sqrt(max(a2 + b2 - 2*dot, 4))   == relu(dist-2) + 2
//   y = relu(min(|dy|, 2pi-|dy|) - pi/3)
//   m = min(m, s + y)
__global__ __launch_bounds__(256) void cm_main(
    const float4* __restrict__ ws_nodes,   // per-node float4
    const float4* __restrict__ ws_pts,     // per-point float4
    float*        __restrict__ ws_part)    // (B, CH, KT)
{
  const int b   = blockIdx.x >> 5;          // / CH_
  const int c   = blockIdx.x & (CH_ - 1);
  const int tid = threadIdx.x;

  __shared__ float4 nd[CSZ_];
  if (tid < CSZ_) {
    nd[tid] = ws_nodes[(size_t)b * NODES_ + c * CSZ_ + tid];
  }

  const int kt0 = tid;
  const int kt1 = tid + 256;                // valid iff < 480
  const float4 p0 = ws_pts[(size_t)b * KT_ + kt0];
  const float4 p1 = (kt1 < KT_) ? ws_pts[(size_t)b * KT_ + kt1]
                                : make_float4(0.f, 0.f, 0.f, 0.f);
  __syncthreads();

  float m0 = INFINITY, m1 = INFINITY;
  #pragma unroll 8
  for (int i = 0; i < CSZ_; ++i) {
    const float4 nv = nd[i];                // broadcast, conflict-free
    {
      float t = nv.z + p0.z;                // a2 + b2
      t = fmaf(nv.x, p0.x, t);              // -2*nx*px
      t = fmaf(nv.y, p0.y, t);
      t = fmaxf(t, 4.0f);
      const float s  = __builtin_amdgcn_sqrtf(t);
      const float yd = nv.w - p0.w;
      const float w2 = TWO_PI_F - fabsf(yd);
      const float a  = fminf(fabsf(yd), w2);
      const float yc = fmaxf(a - YAW_TH_F, 0.0f);
      m0 = fminf(m0, s + yc);
    }
    {
      float t = nv.z + p1.z;
      t = fmaf(nv.x, p1.x, t);
      t = fmaf(nv.y, p1.y, t);
      t = fmaxf(t, 4.0f);
      const float s  = __builtin_amdgcn_sqrtf(t);
      const float yd = nv.w - p1.w;
      const float w2 = TWO_PI_F - fabsf(yd);
      const float a  = fminf(fabsf(yd), w2);
      const float yc = fmaxf(a - YAW_TH_F, 0.0f);
      m1 = fminf(m1, s + yc);
    }
  }

  // transposed layout: [b][c][kt] -> coalesced store AND coalesced reduce load
  float* wp = ws_part + ((size_t)b * CH_ + c) * KT_;
  wp[kt0] = m0;
  if (kt1 < KT_) wp[kt1] = m1;
}

// ---------------------------------------------------------------------------
// Kernel 2: min over chunks (coalesced), subtract hoisted 2, sum over T.
__global__ __launch_bounds__(512) void cm_reduce(
    const float* __restrict__ ws_part, float* __restrict__ out)
{
  const int b   = blockIdx.x;
  const int tid = threadIdx.x;
  __shared__ float sc[KT_];

  if (tid < KT_) {
    const float* wp = ws_part + (size_t)b * CH_ * KT_;
    float m = INFINITY;
    #pragma unroll
    for (int c = 0; c < CH_; ++c) m = fminf(m, wp[c * KT_ + tid]);
    sc[tid] = m - 2.0f;                     // restore the hoisted -2
  }
  __syncthreads();

  if (tid < K_) {
    float s = 0.0f;
    #pragma unroll
    for (int t = 0; t < T_; ++t) s += sc[tid * T_ + t];
    out[b * K_ + tid] = s;
  }
}

// ---------------------------------------------------------------------------
extern "C" void kernel_launch(void* const* d_in, const int* in_sizes, int n_in,
                              void* d_out, int out_size, void* d_ws, size_t ws_size,
                              hipStream_t stream) {
  const float* preds = (const float*)d_in[0];
  const float* cn    = (const float*)d_in[1];
  const int*   cmask = (const int*)d_in[2];
  float* out = (float*)d_out;
  float4* ws4 = (float4*)d_ws;
  float*  ws_part = (float*)(ws4 + WS_PART_OFF4);  // 32*32*480 floats = 1.97 MB

  // 97280 work items = exactly 380 blocks of 256
  cm_prep<<<dim3((NNODE_TOT + NPT_TOT) / 256), dim3(256), 0, stream>>>(
      preds, cn, cmask, ws4);
  cm_main<<<dim3(B_ * CH_), dim3(256), 0, stream>>>(
      ws4, ws4 + WS_PTS_OFF, ws_part);
  cm_reduce<<<dim3(B_), dim3(512), 0, stream>>>(ws_part, out);
}